// Round 6
// baseline (1254.432 us; speedup 1.0000x reference)
//
#include <hip/hip_runtime.h>

#define NPOS    65536      // B*D*H*W
#define CDIM    64
#define KCODES  1024
#define SPATIAL 16384      // D*H*W
#define QELEMS  4194304    // B*C*D*H*W

#define PB      64         // positions per block
#define KB      128        // codes per K-pass
#define NPASS   8          // KCODES/KB
#define SLICE_C 16         // c per staged E slice
#define NSLICE  4          // CDIM/SLICE_C
#define P_THR   8          // positions per thread
#define K_THR   4          // codes per thread per pass
#define XPAD    68         // padded X row (floats) -> bank spread, 16B-aligned rows

#define LOSS_IDX 1024      // wsf[0..1023] = code norms, wsf[1024] = loss accum

__global__ void k_norms(const float* __restrict__ emb, float* __restrict__ wsf) {
    const int k = blockIdx.x * 256 + threadIdx.x;   // grid exactly covers 1024
    if (k == 0) wsf[LOSS_IDX] = 0.0f;
    const float4* e4 = (const float4*)(emb + (size_t)k * CDIM);
    float s = 0.0f;
#pragma unroll
    for (int c = 0; c < CDIM / 4; ++c) {
        float4 e = e4[c];
        s += e.x * e.x + e.y * e.y + e.z * e.z + e.w * e.w;
    }
    wsf[k] = s;
}

__global__ __launch_bounds__(256, 4) void k_fused(const float* __restrict__ z_e,
                                                  const float* __restrict__ emb,
                                                  float* __restrict__ out,
                                                  float* __restrict__ wsf) {
    __shared__ float X[PB][XPAD];                 // 17.4 KB, z_e tile (later quantized in place)
    __shared__ float E[2][SLICE_C][KB];           // 16 KB, double-buffered transposed E slice
    __shared__ unsigned long long bestp[PB];      // 0.5 KB

    const int t    = threadIdx.x;
    const int n0   = blockIdx.x * PB;
    const int b    = n0 >> 14;
    const int dhw0 = n0 & (SPATIAL - 1);
    const float* zb = z_e + (size_t)b * (CDIM * SPATIAL) + dhw0;

    // ---- stage X tile [64 pos][64 c]: coalesced 256B segments per c ----
#pragma unroll
    for (int i = 0; i < 16; ++i) {
        const int idx = i * 256 + t;
        const int c = idx >> 6, p = idx & 63;
        X[p][c] = zb[(size_t)c * SPATIAL + p];
    }
    if (t < PB) bestp[t] = ~0ull;

    const int tp = t >> 5;   // 0..7  position group (8 positions, stride 8)
    const int tk = t & 31;   // 0..31 code group (4 contiguous codes per pass)

    // ---- prologue: stage E slice (pass0, slice0) into buf0, transposed [c][k] ----
    {
        const float* src = emb + (size_t)(t >> 1) * CDIM + (t & 1) * 8;
        float4 a  = *(const float4*)src;
        float4 c4 = *(const float4*)(src + 4);
        const int wk = t >> 1, ch = (t & 1) * 8;
        E[0][ch+0][wk]=a.x;  E[0][ch+1][wk]=a.y;  E[0][ch+2][wk]=a.z;  E[0][ch+3][wk]=a.w;
        E[0][ch+4][wk]=c4.x; E[0][ch+5][wk]=c4.y; E[0][ch+6][wk]=c4.z; E[0][ch+7][wk]=c4.w;
    }
    __syncthreads();

    unsigned long long best8[P_THR];
#pragma unroll
    for (int i = 0; i < P_THR; ++i) best8[i] = ~0ull;

    float acc[P_THR][K_THR];
    float4 nrm4 = make_float4(0.f, 0.f, 0.f, 0.f);

    for (int ss = 0; ss < NPASS * NSLICE; ++ss) {
        const int pass = ss >> 2;
        const int sl   = ss & 3;
        const int buf  = ss & 1;

        // issue next-slice global loads EARLY (latency hides under compute)
        float4 ga, gb;
        const bool have = (ss + 1 < NPASS * NSLICE);
        if (have) {
            const int np = (ss + 1) >> 2, nsl = (ss + 1) & 3;
            const float* src = emb + (size_t)(np * KB + (t >> 1)) * CDIM + nsl * SLICE_C + (t & 1) * 8;
            ga = *(const float4*)src;
            gb = *(const float4*)(src + 4);
        }

        if (sl == 0) {
            nrm4 = *(const float4*)(wsf + pass * KB + tk * 4);
#pragma unroll
            for (int i = 0; i < P_THR; ++i)
#pragma unroll
                for (int j = 0; j < K_THR; ++j) acc[i][j] = 0.0f;
        }

        const int cb = sl * SLICE_C;
#pragma unroll
        for (int st = 0; st < 4; ++st) {
            const int cl = 4 * st;
            float4 e0 = *(const float4*)&E[buf][cl + 0][tk * 4];
            float4 e1 = *(const float4*)&E[buf][cl + 1][tk * 4];
            float4 e2 = *(const float4*)&E[buf][cl + 2][tk * 4];
            float4 e3 = *(const float4*)&E[buf][cl + 3][tk * 4];
#pragma unroll
            for (int i = 0; i < P_THR; ++i) {
                float4 xv = *(const float4*)&X[tp + 8 * i][cb + cl];
                acc[i][0] = fmaf(xv.x, e0.x, acc[i][0]);
                acc[i][1] = fmaf(xv.x, e0.y, acc[i][1]);
                acc[i][2] = fmaf(xv.x, e0.z, acc[i][2]);
                acc[i][3] = fmaf(xv.x, e0.w, acc[i][3]);
                acc[i][0] = fmaf(xv.y, e1.x, acc[i][0]);
                acc[i][1] = fmaf(xv.y, e1.y, acc[i][1]);
                acc[i][2] = fmaf(xv.y, e1.z, acc[i][2]);
                acc[i][3] = fmaf(xv.y, e1.w, acc[i][3]);
                acc[i][0] = fmaf(xv.z, e2.x, acc[i][0]);
                acc[i][1] = fmaf(xv.z, e2.y, acc[i][1]);
                acc[i][2] = fmaf(xv.z, e2.z, acc[i][2]);
                acc[i][3] = fmaf(xv.z, e2.w, acc[i][3]);
                acc[i][0] = fmaf(xv.w, e3.x, acc[i][0]);
                acc[i][1] = fmaf(xv.w, e3.y, acc[i][1]);
                acc[i][2] = fmaf(xv.w, e3.z, acc[i][2]);
                acc[i][3] = fmaf(xv.w, e3.w, acc[i][3]);
            }
        }

        if (sl == 3) {   // pass complete: score + running argmin (global-k minor => first-occurrence)
            const float nv[4] = {nrm4.x, nrm4.y, nrm4.z, nrm4.w};
#pragma unroll
            for (int j = 0; j < K_THR; ++j) {
                const unsigned gk = (unsigned)(pass * KB + tk * 4 + j);
#pragma unroll
                for (int i = 0; i < P_THR; ++i) {
                    float s = fmaf(-2.0f, acc[i][j], nv[j]);
                    unsigned u = __float_as_uint(s);
                    unsigned mono = (u & 0x80000000u) ? ~u : (u | 0x80000000u);
                    unsigned long long pk = ((unsigned long long)mono << 10) | gk;
                    if (pk < best8[i]) best8[i] = pk;
                }
            }
        }

        if (have) {      // write prefetched slice into the other buffer
            const int nb = buf ^ 1;
            const int wk = t >> 1, ch = (t & 1) * 8;
            E[nb][ch+0][wk]=ga.x; E[nb][ch+1][wk]=ga.y; E[nb][ch+2][wk]=ga.z; E[nb][ch+3][wk]=ga.w;
            E[nb][ch+4][wk]=gb.x; E[nb][ch+5][wk]=gb.y; E[nb][ch+6][wk]=gb.z; E[nb][ch+7][wk]=gb.w;
        }
        __syncthreads();
    }

    // ---- reduce across the 32 tk lanes (xor stays within the 32-lane tk field) ----
#pragma unroll
    for (int off = 1; off < 32; off <<= 1) {
#pragma unroll
        for (int i = 0; i < P_THR; ++i) {
            unsigned long long o = __shfl_xor(best8[i], off, 64);
            if (o < best8[i]) best8[i] = o;
        }
    }
    if (tk == 0) {
#pragma unroll
        for (int i = 0; i < P_THR; ++i) bestp[tp + 8 * i] = best8[i];
    }
    __syncthreads();

    // ---- fused epilogue: gather e, quantize in place in X, loss ----
    const int p    = t >> 2;
    const int q4   = t & 3;
    const int bidx = (int)(bestp[p] & 1023ull);
    if (q4 == 0) out[QELEMS + 2 + n0 + p] = (float)bidx;   // indices (f32)

    float lsum = 0.0f;
    const float* ep = emb + (size_t)bidx * CDIM + q4 * 16;
#pragma unroll
    for (int s4 = 0; s4 < 4; ++s4) {
        float4 ev = *(const float4*)(ep + 4 * s4);
        const int c = q4 * 16 + 4 * s4;
        float4 xv = *(const float4*)&X[p][c];
        float d0 = ev.x - xv.x, d1 = ev.y - xv.y, d2 = ev.z - xv.z, d3 = ev.w - xv.w;
        float4 qv = make_float4(xv.x + d0, xv.y + d1, xv.z + d2, xv.w + d3);  // straight-through
        *(float4*)&X[p][c] = qv;
        lsum = fmaf(d0, d0, lsum); lsum = fmaf(d1, d1, lsum);
        lsum = fmaf(d2, d2, lsum); lsum = fmaf(d3, d3, lsum);
    }
#pragma unroll
    for (int off = 32; off > 0; off >>= 1) lsum += __shfl_down(lsum, off, 64);
    if ((t & 63) == 0) atomicAdd(&wsf[LOSS_IDX], lsum);
    __syncthreads();

    // ---- coalesced write-out: per instr, 64 lanes = 256B contiguous segment ----
    const int pw = t & 63;
    const int cg = t >> 6;
    float* qb = out + (size_t)b * (CDIM * SPATIAL) + dhw0 + pw;
#pragma unroll
    for (int j = 0; j < 16; ++j) {
        const int c = cg + 4 * j;
        qb[(size_t)c * SPATIAL] = X[pw][c];
    }
}

__global__ void k_loss(const float* __restrict__ wsf, float* __restrict__ out) {
    const float m = wsf[LOSS_IDX] / (float)QELEMS;
    out[QELEMS]     = m;  // codebook_loss
    out[QELEMS + 1] = m;  // commitment_loss (same forward value)
}

extern "C" void kernel_launch(void* const* d_in, const int* in_sizes, int n_in,
                              void* d_out, int out_size, void* d_ws, size_t ws_size,
                              hipStream_t stream) {
    const float* z_e = (const float*)d_in[0];
    const float* emb = (const float*)d_in[1];
    float*       out = (float*)d_out;
    float*       wsf = (float*)d_ws;

    k_norms<<<KCODES / 256, 256, 0, stream>>>(emb, wsf);      // also zeroes loss accum
    k_fused<<<NPOS / PB, 256, 0, stream>>>(z_e, emb, out, wsf);
    k_loss<<<1, 1, 0, stream>>>(wsf, out);
}

// Round 8
// 223.997 us; speedup vs baseline: 5.6002x; 5.6002x over previous
//
#include <hip/hip_runtime.h>

#define NPOS    65536      // B*D*H*W
#define CDIM    64
#define KCODES  1024
#define SPATIAL 16384      // D*H*W
#define QELEMS  4194304    // B*C*D*H*W

#define PB      64         // positions per block
#define NT      64         // codes per tile
#define NTILE   16         // KCODES / NT
#define XPAD    68         // padded row: 68*4B = 272B, 16B-aligned, bank-spread

#define LOSS_IDX 1024      // wsf[0..1023] = code norms; wsf[1024] = loss accumulator

__global__ void k_norms(const float* __restrict__ emb, float* __restrict__ wsf) {
    const int k = blockIdx.x * 256 + threadIdx.x;   // grid covers exactly 1024
    if (k == 0) wsf[LOSS_IDX] = 0.0f;
    const float4* e4 = (const float4*)(emb + (size_t)k * CDIM);
    float s = 0.0f;
#pragma unroll
    for (int c = 0; c < CDIM / 4; ++c) {
        float4 e = e4[c];
        s += e.x * e.x + e.y * e.y + e.z * e.z + e.w * e.w;
    }
    wsf[k] = s;
}

// FMA micro-tile: 4 channels (XV.x..w == ch 4k4..4k4+3) x 4 codes
#define FMA16(i, XV) \
    acc[i][0] = fmaf(XV.x, ev0.x, acc[i][0]); acc[i][1] = fmaf(XV.x, ev0.y, acc[i][1]); \
    acc[i][2] = fmaf(XV.x, ev0.z, acc[i][2]); acc[i][3] = fmaf(XV.x, ev0.w, acc[i][3]); \
    acc[i][0] = fmaf(XV.y, ev1.x, acc[i][0]); acc[i][1] = fmaf(XV.y, ev1.y, acc[i][1]); \
    acc[i][2] = fmaf(XV.y, ev1.z, acc[i][2]); acc[i][3] = fmaf(XV.y, ev1.w, acc[i][3]); \
    acc[i][0] = fmaf(XV.z, ev2.x, acc[i][0]); acc[i][1] = fmaf(XV.z, ev2.y, acc[i][1]); \
    acc[i][2] = fmaf(XV.z, ev2.z, acc[i][2]); acc[i][3] = fmaf(XV.z, ev2.w, acc[i][3]); \
    acc[i][0] = fmaf(XV.w, ev3.x, acc[i][0]); acc[i][1] = fmaf(XV.w, ev3.y, acc[i][1]); \
    acc[i][2] = fmaf(XV.w, ev3.z, acc[i][2]); acc[i][3] = fmaf(XV.w, ev3.w, acc[i][3]);

__global__ void k_fused(const float* __restrict__ z_e,
                        const float* __restrict__ emb,
                        float* __restrict__ out,
                        float* __restrict__ wsf) {
    __shared__ float X[PB][XPAD];                 // 17.0 KB  z_e tile (quantized in place later)
    __shared__ float ET[CDIM][XPAD];              // 17.0 KB  E-tile transposed: ET[ch][code]
    __shared__ float NRM[KCODES];                 // 4 KB
    __shared__ unsigned long long bestp[PB];      // 0.5 KB

    const int t    = threadIdx.x;
    const int tx   = t & 15;           // code dim (4 codes/thread)
    const int ty   = t >> 4;           // pos dim  (4 positions/thread)
    const int n0   = blockIdx.x * PB;
    const int b    = n0 >> 14;
    const int dhw0 = n0 & (SPATIAL - 1);
    const float* zb = z_e + (size_t)b * (CDIM * SPATIAL) + dhw0;

    // ---- stage X tile [64 pos][64 ch]: per wave, one ch = 256B contiguous global read ----
#pragma unroll
    for (int i = 0; i < 16; ++i) {
        const int idx = i * 256 + t;
        const int c = idx >> 6, p = idx & 63;
        X[p][c] = zb[(size_t)c * SPATIAL + p];
    }
    // ---- stage norms (1024 floats) ----
    *(float4*)&NRM[t * 4] = *(const float4*)(wsf + t * 4);

    // ---- prefetch E tile 0 into regs (16 floats of one code row per thread) ----
    const int crow  = t >> 2;          // 0..63: code row within tile
    const int cpart = (t & 3) * 16;    // channel quarter
    float4 g0, g1, g2, g3;
    {
        const float* src = emb + (size_t)crow * CDIM + cpart;
        g0 = *(const float4*)(src + 0);  g1 = *(const float4*)(src + 4);
        g2 = *(const float4*)(src + 8);  g3 = *(const float4*)(src + 12);
    }

    unsigned long long best4[4] = {~0ull, ~0ull, ~0ull, ~0ull};

#pragma unroll 1
    for (int tile = 0; tile < NTILE; ++tile) {
        __syncthreads();   // ET free (prev compute done); covers X/NRM staging on tile 0
        // write prefetched tile into ET (transposed)
        ET[cpart +  0][crow] = g0.x; ET[cpart +  1][crow] = g0.y;
        ET[cpart +  2][crow] = g0.z; ET[cpart +  3][crow] = g0.w;
        ET[cpart +  4][crow] = g1.x; ET[cpart +  5][crow] = g1.y;
        ET[cpart +  6][crow] = g1.z; ET[cpart +  7][crow] = g1.w;
        ET[cpart +  8][crow] = g2.x; ET[cpart +  9][crow] = g2.y;
        ET[cpart + 10][crow] = g2.z; ET[cpart + 11][crow] = g2.w;
        ET[cpart + 12][crow] = g3.x; ET[cpart + 13][crow] = g3.y;
        ET[cpart + 14][crow] = g3.z; ET[cpart + 15][crow] = g3.w;
        // issue next-tile prefetch early (latency hides under compute)
        if (tile + 1 < NTILE) {
            const float* src = emb + (size_t)((tile + 1) * NT + crow) * CDIM + cpart;
            g0 = *(const float4*)(src + 0);  g1 = *(const float4*)(src + 4);
            g2 = *(const float4*)(src + 8);  g3 = *(const float4*)(src + 12);
        }
        __syncthreads();   // ET ready

        float acc[4][4];
#pragma unroll
        for (int i = 0; i < 4; ++i)
#pragma unroll
            for (int j = 0; j < 4; ++j) acc[i][j] = 0.0f;

        for (int k4 = 0; k4 < 16; ++k4) {
            float4 ev0 = *(const float4*)&ET[4 * k4 + 0][4 * tx];
            float4 ev1 = *(const float4*)&ET[4 * k4 + 1][4 * tx];
            float4 ev2 = *(const float4*)&ET[4 * k4 + 2][4 * tx];
            float4 ev3 = *(const float4*)&ET[4 * k4 + 3][4 * tx];
            float4 xv0 = *(const float4*)&X[4 * ty + 0][4 * k4];
            float4 xv1 = *(const float4*)&X[4 * ty + 1][4 * k4];
            float4 xv2 = *(const float4*)&X[4 * ty + 2][4 * k4];
            float4 xv3 = *(const float4*)&X[4 * ty + 3][4 * k4];
            FMA16(0, xv0)
            FMA16(1, xv1)
            FMA16(2, xv2)
            FMA16(3, xv3)
        }

        // scores + running argmin (global k minor bits => numpy first-occurrence tie-break)
        const float4 nr = *(const float4*)&NRM[tile * NT + 4 * tx];
#pragma unroll
        for (int j = 0; j < 4; ++j) {
            const float nvj = (j == 0 ? nr.x : j == 1 ? nr.y : j == 2 ? nr.z : nr.w);
            const unsigned gk = (unsigned)(tile * NT + 4 * tx + j);
#pragma unroll
            for (int i = 0; i < 4; ++i) {
                const float s = fmaf(-2.0f, acc[i][j], nvj);
                unsigned u    = __float_as_uint(s);
                unsigned mono = (u & 0x80000000u) ? ~u : (u | 0x80000000u);
                unsigned long long pk = ((unsigned long long)mono << 10) | gk;
                if (pk < best4[i]) best4[i] = pk;
            }
        }
    }

    // ---- reduce argmin across the 16 tx lanes of each row group ----
#pragma unroll
    for (int off = 1; off < 16; off <<= 1) {
#pragma unroll
        for (int i = 0; i < 4; ++i) {
            unsigned long long o = __shfl_xor(best4[i], off, 16);
            if (o < best4[i]) best4[i] = o;
        }
    }
    if (tx == 0) {
#pragma unroll
        for (int i = 0; i < 4; ++i) bestp[4 * ty + i] = best4[i];
    }
    __syncthreads();

    // ---- fused epilogue: gather e (L2-hot), quantize X in place, loss ----
    const int p    = t >> 2;
    const int q4   = t & 3;
    const int bidx = (int)(bestp[p] & 1023ull);
    if (q4 == 0) out[QELEMS + 2 + n0 + p] = (float)bidx;   // indices (f32)

    float lsum = 0.0f;
    const float* eprow = emb + (size_t)bidx * CDIM + q4 * 16;
#pragma unroll
    for (int s4 = 0; s4 < 4; ++s4) {
        float4 ev = *(const float4*)(eprow + 4 * s4);
        const int c = q4 * 16 + 4 * s4;
        float4 xv = *(const float4*)&X[p][c];
        float d0 = ev.x - xv.x, d1 = ev.y - xv.y, d2 = ev.z - xv.z, d3 = ev.w - xv.w;
        *(float4*)&X[p][c] = make_float4(xv.x + d0, xv.y + d1, xv.z + d2, xv.w + d3);
        lsum = fmaf(d0, d0, lsum); lsum = fmaf(d1, d1, lsum);
        lsum = fmaf(d2, d2, lsum); lsum = fmaf(d3, d3, lsum);
    }
#pragma unroll
    for (int off = 32; off > 0; off >>= 1) lsum += __shfl_down(lsum, off, 64);
    if ((t & 63) == 0) atomicAdd(&wsf[LOSS_IDX], lsum);
    __syncthreads();

    // ---- coalesced write-out: per instr, 64 lanes = 256B contiguous segment ----
    const int pw = t & 63;
    const int cg = t >> 6;
    float* qb = out + (size_t)b * (CDIM * SPATIAL) + dhw0 + pw;
#pragma unroll
    for (int j = 0; j < 16; ++j) {
        const int c = cg + 4 * j;
        qb[(size_t)c * SPATIAL] = X[pw][c];
    }
}

__global__ void k_loss(const float* __restrict__ wsf, float* __restrict__ out) {
    const float m = wsf[LOSS_IDX] / (float)QELEMS;
    out[QELEMS]     = m;  // codebook_loss
    out[QELEMS + 1] = m;  // commitment_loss (same forward value)
}

extern "C" void kernel_launch(void* const* d_in, const int* in_sizes, int n_in,
                              void* d_out, int out_size, void* d_ws, size_t ws_size,
                              hipStream_t stream) {
    const float* z_e = (const float*)d_in[0];
    const float* emb = (const float*)d_in[1];
    float*       out = (float*)d_out;
    float*       wsf = (float*)d_ws;

    k_norms<<<KCODES / 256, 256, 0, stream>>>(emb, wsf);      // also zeroes loss accum
    k_fused<<<NPOS / PB, 256, 0, stream>>>(z_e, emb, out, wsf);
    k_loss<<<1, 1, 0, stream>>>(wsf, out);
}